// Round 5
// baseline (249.324 us; speedup 1.0000x reference)
//
#include <hip/hip_runtime.h>

// LengthRegulator: B=32, T=1024, D=384, T_OUT=4096
// out[b, p, :] = x[b, t(p), :] where t(p) = #{t : ends[t] <= p} (searchsorted
// right of inclusive-cumsum of max(dur,0)), valid for p < min(total, target).

#define BB 32
#define TT 1024
#define DD 384
#define TOUT 4096
#define D4 (DD / 4)          // 96 float4 per row
#define N4 (TOUT * D4)       // 393216 float4 per batch
#define EPB 2048             // float4 per gather block (8 per thread)

typedef float v4f __attribute__((ext_vector_type(4)));

// Kernel A: one block per batch. Inclusive scan of clamped durations ->
// ends[B,1024] in global, plus limit[b] = min(total, target_len).
__global__ __launch_bounds__(256) void lr_scan(
    const int4* __restrict__ dur4,      // [B, 256] (durations viewed as int4)
    const int* __restrict__ target_len, // [B]
    int4* __restrict__ ends4,           // [B, 256] (ends viewed as int4, ws)
    int* __restrict__ limit)            // [B] (ws)
{
    __shared__ int sums[256];
    const int b = blockIdx.x;
    const int q = threadIdx.x;

    int4 d = dur4[b * 256 + q];
    const int d0 = d.x > 0 ? d.x : 0;
    const int d1 = d.y > 0 ? d.y : 0;
    const int d2 = d.z > 0 ? d.z : 0;
    const int d3 = d.w > 0 ? d.w : 0;
    const int e0 = d0, e1 = e0 + d1, e2 = e1 + d2, e3 = e2 + d3;
    sums[q] = e3;
    __syncthreads();

    // Hillis-Steele inclusive scan over 256 thread-sums (8 steps).
    #pragma unroll
    for (int off = 1; off < 256; off <<= 1) {
        int u = (q >= off) ? sums[q - off] : 0;
        __syncthreads();
        sums[q] += u;
        __syncthreads();
    }
    const int base = sums[q] - e3;  // exclusive prefix for this thread's 4
    ends4[b * 256 + q] = make_int4(base + e0, base + e1, base + e2, base + e3);

    if (q == 255) {
        const int total = base + e3;
        const int tl = target_len[b];
        limit[b] = total < tl ? total : tl;
    }
}

// Kernel B: fused search + gather. Each block covers 2048 consecutive float4
// (~22 output rows) of one batch. ends[b] is staged to LDS (1 int4/thread);
// 24 threads binary-search one row each into t_row[] (a wave's 64 lanes span
// <2 rows, so per-element searches would be 64x redundant). Then 8 float4
// per thread, strided by 256: every store instruction writes 64 consecutive
// float4 per wave (1 KB contiguous -> full HBM lines, NT-safe).
__global__ __launch_bounds__(256) void lr_gather(
    const v4f* __restrict__ x,        // [B, T, D4]
    const int4* __restrict__ ends4,   // [B, 256]
    const int* __restrict__ limit,    // [B]
    v4f* __restrict__ out)            // [B, TOUT, D4]
{
    __shared__ int s_ends[TT];
    __shared__ int s_trow[24];
    const int b = blockIdx.y;
    const int tid = threadIdx.x;
    const int base0 = blockIdx.x * EPB;
    const int p0 = base0 / D4;

    ((int4*)s_ends)[tid] = ends4[b * 256 + tid];
    const int lim = limit[b];
    __syncthreads();

    if (tid < 24) {
        const int p = p0 + tid;
        int lo = 0;
        #pragma unroll
        for (int s = 512; s > 0; s >>= 1) {
            lo += (s_ends[lo + s - 1] <= p) ? s : 0;   // lo stays <= 1023
        }
        s_trow[tid] = lo;
    }
    __syncthreads();

    const v4f* __restrict__ x_b = x + b * TT * D4;
    v4f* __restrict__ out_b = out + b * N4;

    #pragma unroll
    for (int k = 0; k < 8; ++k) {
        const int i = base0 + k * 256 + tid;
        const int p = i / D4;            // magic-mul division
        const int c = i - p * D4;
        const int t = s_trow[p - p0];    // LDS broadcast (1-2 rows per wave)
        v4f v = (v4f)(0.f);
        if (p < lim) v = x_b[t * D4 + c];
        __builtin_nontemporal_store(v, out_b + i);
    }
}

extern "C" void kernel_launch(void* const* d_in, const int* in_sizes, int n_in,
                              void* d_out, int out_size, void* d_ws, size_t ws_size,
                              hipStream_t stream) {
    const float* x        = (const float*)d_in[0];
    const int* durations  = (const int*)d_in[1];
    const int* target_len = (const int*)d_in[2];
    float* out            = (float*)d_out;

    // Workspace: limit[32] at offset 0 (pad to 64 ints), ends[B*1024] after.
    int* limit = (int*)d_ws;
    int* ends  = (int*)d_ws + 64;

    lr_scan<<<BB, 256, 0, stream>>>((const int4*)durations, target_len,
                                    (int4*)ends, limit);

    dim3 grid(N4 / EPB, BB);  // 192 x 32 blocks
    lr_gather<<<grid, 256, 0, stream>>>((const v4f*)x, (const int4*)ends,
                                        limit, (v4f*)out);
}

// Round 6
// 243.132 us; speedup vs baseline: 1.0255x; 1.0255x over previous
//
#include <hip/hip_runtime.h>

// LengthRegulator: B=32, T=1024, D=384, T_OUT=4096
// out[b, p, :] = x[b, t(p), :] where t(p) = #{t : ends[t] <= p} (searchsorted
// right of inclusive-cumsum of max(dur,0)), valid for p < min(total, target).

#define BB 32
#define TT 1024
#define DD 384
#define TOUT 4096
#define D4 (DD / 4)          // 96 float4 per row
#define N4 (TOUT * D4)       // 393216 float4 per batch
#define EPB 3072             // float4 per gather block = exactly 32 rows
#define ROWS_PB 32
#define KPT 12               // float4 per thread (EPB / 256)

typedef float v4f __attribute__((ext_vector_type(4)));

// Kernel A: one block per batch. Inclusive scan of clamped durations ->
// ends[B,1024] in global, plus limit[b] = min(total, target_len).
__global__ __launch_bounds__(256) void lr_scan(
    const int4* __restrict__ dur4,      // [B, 256] (durations viewed as int4)
    const int* __restrict__ target_len, // [B]
    int4* __restrict__ ends4,           // [B, 256] (ends viewed as int4, ws)
    int* __restrict__ limit)            // [B] (ws)
{
    __shared__ int sums[256];
    const int b = blockIdx.x;
    const int q = threadIdx.x;

    int4 d = dur4[b * 256 + q];
    const int d0 = d.x > 0 ? d.x : 0;
    const int d1 = d.y > 0 ? d.y : 0;
    const int d2 = d.z > 0 ? d.z : 0;
    const int d3 = d.w > 0 ? d.w : 0;
    const int e0 = d0, e1 = e0 + d1, e2 = e1 + d2, e3 = e2 + d3;
    sums[q] = e3;
    __syncthreads();

    // Hillis-Steele inclusive scan over 256 thread-sums (8 steps).
    #pragma unroll
    for (int off = 1; off < 256; off <<= 1) {
        int u = (q >= off) ? sums[q - off] : 0;
        __syncthreads();
        sums[q] += u;
        __syncthreads();
    }
    const int base = sums[q] - e3;  // exclusive prefix for this thread's 4
    ends4[b * 256 + q] = make_int4(base + e0, base + e1, base + e2, base + e3);

    if (q == 255) {
        const int total = base + e3;
        const int tl = target_len[b];
        limit[b] = total < tl ? total : tl;
    }
}

// Kernel B: fused search + gather. Each block covers exactly 32 output rows
// (3072 float4) of one batch. ends[b] staged to LDS; 32 threads binary-search
// one row each into s_trow. Then 12 float4/thread strided by 256: indices and
// row ids computed first, all 12 x loads issued back-to-back (unconditional,
// t always in [0,1023] -> valid address; MLP under vmcnt), then the p>=lim
// zeroing by register select and 12 NT stores (full 4KB contiguous lines per
// wave-instruction -> NT-safe, keeps L2 for x).
__global__ __launch_bounds__(256) void lr_gather(
    const v4f* __restrict__ x,        // [B, T, D4]
    const int4* __restrict__ ends4,   // [B, 256]
    const int* __restrict__ limit,    // [B]
    v4f* __restrict__ out)            // [B, TOUT, D4]
{
    __shared__ int s_ends[TT];
    __shared__ int s_trow[ROWS_PB];
    const int b = blockIdx.y;
    const int tid = threadIdx.x;
    const int base0 = blockIdx.x * EPB;
    const int p0 = blockIdx.x * ROWS_PB;

    ((int4*)s_ends)[tid] = ends4[b * 256 + tid];
    const int lim = limit[b];
    __syncthreads();

    if (tid < ROWS_PB) {
        const int p = p0 + tid;
        int lo = 0;
        #pragma unroll
        for (int s = 512; s > 0; s >>= 1) {
            lo += (s_ends[lo + s - 1] <= p) ? s : 0;   // lo stays in [0,1023]
        }
        s_trow[tid] = lo;
    }
    __syncthreads();

    const v4f* __restrict__ x_b = x + b * TT * D4;
    v4f* __restrict__ out_b = out + b * N4;

    int pp[KPT], cc[KPT], tt[KPT];
    v4f v[KPT];
    #pragma unroll
    for (int k = 0; k < KPT; ++k) {
        const int i = base0 + k * 256 + tid;
        const int p = i / D4;            // magic-mul division
        pp[k] = p;
        cc[k] = i - p * D4;
        tt[k] = s_trow[p - p0];          // LDS broadcast
    }
    #pragma unroll
    for (int k = 0; k < KPT; ++k) {
        v[k] = x_b[tt[k] * D4 + cc[k]];  // 12 independent loads in flight
    }
    #pragma unroll
    for (int k = 0; k < KPT; ++k) {
        if (pp[k] >= lim) v[k] = (v4f)(0.f);
        __builtin_nontemporal_store(v[k], out_b + base0 + k * 256 + tid);
    }
}

extern "C" void kernel_launch(void* const* d_in, const int* in_sizes, int n_in,
                              void* d_out, int out_size, void* d_ws, size_t ws_size,
                              hipStream_t stream) {
    const float* x        = (const float*)d_in[0];
    const int* durations  = (const int*)d_in[1];
    const int* target_len = (const int*)d_in[2];
    float* out            = (float*)d_out;

    // Workspace: limit[32] at offset 0 (pad to 64 ints), ends[B*1024] after.
    int* limit = (int*)d_ws;
    int* ends  = (int*)d_ws + 64;

    lr_scan<<<BB, 256, 0, stream>>>((const int4*)durations, target_len,
                                    (int4*)ends, limit);

    dim3 grid(N4 / EPB, BB);  // 128 x 32 blocks
    lr_gather<<<grid, 256, 0, stream>>>((const v4f*)x, (const int4*)ends,
                                        limit, (v4f*)out);
}

// Round 7
// 240.447 us; speedup vs baseline: 1.0369x; 1.0112x over previous
//
#include <hip/hip_runtime.h>

// LengthRegulator: B=32, T=1024, D=384, T_OUT=4096
// out[b, p, :] = x[b, t(p), :] where t(p) = #{t : ends[t] <= p} (searchsorted
// right of inclusive-cumsum of max(dur,0)), valid for p < min(total, target).
//
// Single fused kernel: each block covers exactly 32 output rows of one batch
// and recomputes the (cheap, L2-resident) duration scan itself — no separate
// scan dispatch, no ends/limit global round trip.

#define BB 32
#define TT 1024
#define TOUT 4096
#define D4 96                // float4 per row (384/4)
#define N4 (TOUT * D4)       // 393216 float4 per batch
#define EPB 3072             // float4 per block = exactly 32 rows
#define ROWS_PB 32
#define KPT 12               // float4 per thread (EPB / 256)

typedef float v4f __attribute__((ext_vector_type(4)));

__global__ __launch_bounds__(256) void lr_fused(
    const int4* __restrict__ dur4,      // [B, 256] (durations viewed as int4)
    const int* __restrict__ target_len, // [B]
    const v4f* __restrict__ x,          // [B, T, D4]
    v4f* __restrict__ out)              // [B, TOUT, D4]
{
    __shared__ int s_ends[TT];
    __shared__ int s_wsum[4];
    __shared__ int s_trow[ROWS_PB];
    const int b = blockIdx.y;
    const int tid = threadIdx.x;
    const int lane = tid & 63;
    const int wave = tid >> 6;
    const int base0 = blockIdx.x * EPB;
    const int p0 = blockIdx.x * ROWS_PB;

    const int tl = target_len[b];               // hoisted, hides under scan

    // ---- in-block duration scan (4 durations/thread, shuffle-based) ----
    int4 d = dur4[b * 256 + tid];
    const int d0 = d.x > 0 ? d.x : 0;
    const int d1 = d.y > 0 ? d.y : 0;
    const int d2 = d.z > 0 ? d.z : 0;
    const int d3 = d.w > 0 ? d.w : 0;
    const int e0 = d0, e1 = e0 + d1, e2 = e1 + d2, e3 = e2 + d3;

    // 64-lane inclusive scan of per-thread sums (6 shuffle steps, no barrier)
    int v = e3;
    #pragma unroll
    for (int off = 1; off < 64; off <<= 1) {
        int u = __shfl_up(v, off, 64);
        if (lane >= off) v += u;
    }
    if (lane == 63) s_wsum[wave] = v;
    __syncthreads();

    int wbase = 0;
    #pragma unroll
    for (int w = 0; w < 3; ++w) wbase += (w < wave) ? s_wsum[w] : 0;
    const int total = s_wsum[0] + s_wsum[1] + s_wsum[2] + s_wsum[3];
    const int lim = total < tl ? total : tl;

    const int base = wbase + v - e3;  // exclusive prefix for this thread's 4
    ((int4*)s_ends)[tid] = make_int4(base + e0, base + e1, base + e2, base + e3);
    __syncthreads();

    // ---- one binary search per output row this block covers ----
    if (tid < ROWS_PB) {
        const int p = p0 + tid;
        int lo = 0;
        #pragma unroll
        for (int s = 512; s > 0; s >>= 1) {
            lo += (s_ends[lo + s - 1] <= p) ? s : 0;   // lo stays in [0,1023]
        }
        s_trow[tid] = lo;
    }
    __syncthreads();

    // ---- gather: 12 float4/thread strided by 256 (wave-contiguous 4 KB
    // stores -> full HBM lines, NT-safe; 12 independent loads in flight) ----
    const v4f* __restrict__ x_b = x + b * TT * D4;
    v4f* __restrict__ out_b = out + b * N4;

    int pp[KPT], cc[KPT], tt[KPT];
    v4f vv[KPT];
    #pragma unroll
    for (int k = 0; k < KPT; ++k) {
        const int i = base0 + k * 256 + tid;
        const int p = i / D4;            // magic-mul division
        pp[k] = p;
        cc[k] = i - p * D4;
        tt[k] = s_trow[p - p0];          // LDS broadcast
    }
    #pragma unroll
    for (int k = 0; k < KPT; ++k) {
        vv[k] = x_b[tt[k] * D4 + cc[k]];
    }
    #pragma unroll
    for (int k = 0; k < KPT; ++k) {
        if (pp[k] >= lim) vv[k] = (v4f)(0.f);
        __builtin_nontemporal_store(vv[k], out_b + base0 + k * 256 + tid);
    }
}

extern "C" void kernel_launch(void* const* d_in, const int* in_sizes, int n_in,
                              void* d_out, int out_size, void* d_ws, size_t ws_size,
                              hipStream_t stream) {
    const float* x        = (const float*)d_in[0];
    const int* durations  = (const int*)d_in[1];
    const int* target_len = (const int*)d_in[2];
    float* out            = (float*)d_out;

    dim3 grid(N4 / EPB, BB);  // 128 x 32 blocks
    lr_fused<<<grid, 256, 0, stream>>>((const int4*)durations, target_len,
                                       (const v4f*)x, (v4f*)out);
}